// Round 17
// baseline (69.993 us; speedup 1.0000x reference)
//
#include <hip/hip_runtime.h>
#include <stdint.h>

#define N_ROWS 8192
#define D_DIM  1024
#define NEG_BIG -1e30f
#define NCHUNK 32
#define CHUNK_J 256
#define NTILE 8               // 8 j-tiles of 32 cols per chunk
#define BUFSZ 13312           // 12 KB staged fp4 data (m 0..11) + 1 KB scales

typedef __attribute__((ext_vector_type(16))) float f32x16;
typedef __attribute__((ext_vector_type(8)))  int   i32x8;
typedef __attribute__((ext_vector_type(4)))  int   i32x4;
typedef __attribute__((ext_vector_type(2)))  long  long2_t;

// exp(10v - 10) = exp2(v*C - C), raw v_exp_f32
#define EXPC 14.4269504089f
#define EXPRAW(dst, v) { float _a = fmaf((v), EXPC, -EXPC);                 \
    asm("v_exp_f32 %0, %1" : "=v"(dst) : "v"(_a)); }

// branchless sorted insert of v into descending 5-list, med3 form
#define INS5(b0,b1,b2,b3,b4,v) {                        \
    float _n4 = __builtin_amdgcn_fmed3f(b3, (v), b4);   \
    float _n3 = __builtin_amdgcn_fmed3f(b2, (v), b3);   \
    float _n2 = __builtin_amdgcn_fmed3f(b1, (v), b2);   \
    float _n1 = __builtin_amdgcn_fmed3f(b0, (v), b1);   \
    b0 = fmaxf(b0, (v)); b1 = _n1; b2 = _n2; b3 = _n3; b4 = _n4; }

// e2m1 encode of x (pre-scaled by inv = 2^-s): grid {0,.5,1,1.5,2,3,4,6}
static __device__ inline uint32_t enc4(float x, float inv) {
    float q = fabsf(x) * inv;
    uint32_t n = q < 0.25f ? 0u : (q < 0.75f ? 1u : (q < 1.25f ? 2u : (q < 1.75f ? 3u :
                 (q < 2.5f  ? 4u : (q < 3.5f  ? 5u : (q < 5.0f  ? 6u : 7u))))));
    return n | (x < 0.f ? 8u : 0u);
}

// ---------------- K1: normalize -> MX-fp4 (e2m1 + per-32-block E8M0) --------
__global__ __launch_bounds__(256) void norm_kernel(const float* __restrict__ z,
                                                   uint8_t* __restrict__ zn4,
                                                   uint8_t* __restrict__ sbq) {
    int wave = threadIdx.x >> 6;
    int lane = threadIdx.x & 63;
    int row  = blockIdx.x * 4 + wave;
    const float* zr = z + (size_t)row * D_DIM;
    float4 c[4];
    float ss = 0.f;
#pragma unroll
    for (int i = 0; i < 4; ++i) {
        c[i] = *(const float4*)(zr + i * 256 + lane * 4);
        ss += c[i].x*c[i].x + c[i].y*c[i].y + c[i].z*c[i].z + c[i].w*c[i].w;
    }
#pragma unroll
    for (int m = 1; m < 64; m <<= 1) ss += __shfl_xor(ss, m);
    float scale = 1.0f / fmaxf(sqrtf(ss), 1e-12f);
    const int J = row >> 5, r31 = row & 31;
    uint8_t* db = zn4 + (size_t)J * 16384;
    uint8_t* sb = sbq + (size_t)J * 1024;
#pragma unroll
    for (int i = 0; i < 4; ++i) {
        float x0 = c[i].x*scale, x1 = c[i].y*scale, x2 = c[i].z*scale, x3 = c[i].w*scale;
        float am = fmaxf(fmaxf(fabsf(x0), fabsf(x1)), fmaxf(fabsf(x2), fabsf(x3)));
        am = fmaxf(am, __shfl_xor(am, 1));
        am = fmaxf(am, __shfl_xor(am, 2));
        am = fmaxf(am, __shfl_xor(am, 4));
        uint32_t ub = __float_as_uint(am);
        int sbyte = (int)(ub >> 23) - 2 + (((ub & 0x7fffffu) > 0x400000u) ? 1 : 0);
        float inv = __uint_as_float((uint32_t)(254 - sbyte) << 23);   // 2^-s
        uint32_t pk = enc4(x0, inv) | (enc4(x1, inv) << 4)
                    | (enc4(x2, inv) << 8) | (enc4(x3, inv) << 12);
        uint32_t pko = __shfl_xor(pk, 1);          // partner lane's 16 bits
        int m  = i * 4 + (lane >> 4);
        int l2 = r31 + 32 * ((lane >> 3) & 1);
        if ((lane & 1) == 0)                        // paired 4B store
            *(uint32_t*)(db + m * 1024 + l2 * 16 + 4 * ((lane & 7) >> 1))
                = pk | (pko << 16);
        if ((lane & 7) == 0) {
            int j = lane >> 3;
            sb[(size_t)(r31 + 32 * (j & 1)) * 16 + i * 4 + (j >> 1)] = (uint8_t)sbyte;
        }
    }
}

// ---------------- K2: fused MX-fp4 sim, split A-source (12 LDS + 4 L2) -------
// grid: 64 i-blocks (128 rows, 32/wave) x 32 j-chunks (256 cols, 8 tiles).
// m 0..11: A from LDS (staged, linear, conflict-free base+l*16 reads).
// m 12..15: A direct from L2 (coalesced 2 KB broadcasts; zn4 is 4 MB,
// L2-resident), issued BEFORE the next-tile STAGE so waiting on them does
// not drain the prefetch queue. No setprio (avoid CU-wide phase convoy).
__global__ __launch_bounds__(256, 2) void sim_kernel(const uint8_t* __restrict__ zn4,
                                                     const uint8_t* __restrict__ sbq,
                                                     float* __restrict__ pstats) {
    __shared__ __align__(16) char lds[2 * BUFSZ];
    const int tid  = threadIdx.x;
    const int w    = tid >> 6;
    const int l    = tid & 63;
    const int r32  = l & 31;
    const int h    = l >> 5;
    const int ib   = blockIdx.x >> 5;
    const int ch   = blockIdx.x & 31;
    const int j0c  = ch * CHUNK_J;
    const int i_lane = ib * 128 + w * 32 + r32;
    const int Ii   = ib * 4 + w;                       // i-tile index 0..255
    const int diag_jt = ((Ii >> 3) == ch) ? (Ii & 7) : -1;
    const char* ldsr = lds + l * 16;

#define GLL(SRC, DST) __builtin_amdgcn_global_load_lds(                         \
        (const __attribute__((address_space(1))) uint32_t*)(SRC),               \
        (__attribute__((address_space(3))) uint32_t*)(DST), 16, 0, 0)

#define STAGE(JTN, BUF) {                                                       \
        const uint8_t* sD_ = zn4 + (size_t)(ch * NTILE + (JTN)) * 16384;        \
        _Pragma("unroll")                                                       \
        for (int mm = 0; mm < 3; ++mm) {                                        \
            int m_ = w * 3 + mm;                                                \
            GLL(sD_ + m_ * 1024 + l * 16, (BUF) + m_ * 1024);                   \
        }                                                                       \
        if (w == 3)                                                             \
            GLL(sbq + (size_t)(ch * NTILE + (JTN)) * 1024 + l * 16,             \
                (BUF) + 12288);                                                 \
    }

    STAGE(0, lds);

    // resident B-operand, packed pairs (even m lower 4 dwords, odd m upper)
    i32x8 bres8[8];
    {
        const uint8_t* rp = zn4 + (size_t)Ii * 16384 + l * 16;
#pragma unroll
        for (int g = 0; g < 8; ++g) {
            *(long2_t*)&bres8[g]       = *(const long2_t*)(rp + (2 * g) * 1024);
            *((long2_t*)&bres8[g] + 1) = *(const long2_t*)(rp + (2 * g + 1) * 1024);
        }
    }
    uint32_t sw_[4];
    {
        const uint32_t* sp = (const uint32_t*)(sbq + (size_t)Ii * 1024 + l * 16);
        sw_[0] = sp[0]; sw_[1] = sp[1]; sw_[2] = sp[2]; sw_[3] = sp[3];
    }

    float s0r = 0.f, s1r = 0.f;
    float b0 = NEG_BIG, b1 = NEG_BIG, b2 = NEG_BIG, b3 = NEG_BIG, b4 = NEG_BIG;
    i32x8 areg = {0,0,0,0,0,0,0,0};
    i32x8 btmp = {0,0,0,0,0,0,0,0};

    __syncthreads();

#define MFMA_E(M) {                                                             \
        asm volatile("" : "+v"(bres8[(M) >> 1]));                               \
        *(long2_t*)&areg = *(const long2_t*)(ldst_ + (M) * 1024);               \
        acc0 = __builtin_amdgcn_mfma_scale_f32_32x32x64_f8f6f4(                 \
            areg, bres8[(M) >> 1], acc0, 4, 4,                                  \
            (M) & 3, sa_[(M) >> 2], (M) & 3, sw_[(M) >> 2]); }
#define MFMA_O(M) {                                                             \
        *(long2_t*)&btmp  = *((const long2_t*)&bres8[(M) >> 1] + 1);            \
        *(long2_t*)&areg = *(const long2_t*)(ldst_ + (M) * 1024);               \
        acc1 = __builtin_amdgcn_mfma_scale_f32_32x32x64_f8f6f4(                 \
            areg, btmp, acc1, 4, 4,                                             \
            (M) & 3, sa_[(M) >> 2], (M) & 3, sw_[(M) >> 2]); }

#define TILE_BODY(JT, CUR) {                                                    \
        /* direct-L2 A loads for m 12..15 of THIS tile, issued first */         \
        const uint8_t* gs_ = zn4 + (size_t)(ch * NTILE + (JT)) * 16384          \
                             + 12 * 1024 + l * 16;                              \
        long2_t g0 = *(const long2_t*)(gs_);                                    \
        long2_t g1 = *(const long2_t*)(gs_ + 1024);                             \
        long2_t g2 = *(const long2_t*)(gs_ + 2048);                             \
        long2_t g3 = *(const long2_t*)(gs_ + 3072);                             \
        if ((JT) + 1 < NTILE) STAGE((JT) + 1, lds + ((CUR) ^ BUFSZ));           \
        const char* ldst_ = ldsr + (CUR);                                       \
        uint32_t sa_[4];                                                        \
        {                                                                       \
            i32x4 sv = *(const i32x4*)(lds + (CUR) + 12288 + l * 16);           \
            sa_[0] = sv[0]; sa_[1] = sv[1]; sa_[2] = sv[2]; sa_[3] = sv[3];     \
        }                                                                       \
        f32x16 acc0, acc1;                                                      \
        _Pragma("unroll")                                                       \
        for (int r = 0; r < 16; ++r) { acc0[r] = 0.f; acc1[r] = 0.f; }          \
        MFMA_E(0)  MFMA_O(1)  MFMA_E(2)  MFMA_O(3)                              \
        MFMA_E(4)  MFMA_O(5)  MFMA_E(6)  MFMA_O(7)                              \
        MFMA_E(8)  MFMA_O(9)  MFMA_E(10) MFMA_O(11)                             \
        /* m 12..15 from L2 registers */                                        \
        asm volatile("" : "+v"(bres8[6]), "+v"(bres8[7]));                      \
        *(long2_t*)&areg = g0;                                                  \
        acc0 = __builtin_amdgcn_mfma_scale_f32_32x32x64_f8f6f4(                 \
            areg, bres8[6], acc0, 4, 4, 0, sa_[3], 0, sw_[3]);                  \
        *(long2_t*)&btmp = *((const long2_t*)&bres8[6] + 1);                    \
        *(long2_t*)&areg = g1;                                                  \
        acc1 = __builtin_amdgcn_mfma_scale_f32_32x32x64_f8f6f4(                 \
            areg, btmp, acc1, 4, 4, 1, sa_[3], 1, sw_[3]);                      \
        *(long2_t*)&areg = g2;                                                  \
        acc0 = __builtin_amdgcn_mfma_scale_f32_32x32x64_f8f6f4(                 \
            areg, bres8[7], acc0, 4, 4, 2, sa_[3], 2, sw_[3]);                  \
        *(long2_t*)&btmp = *((const long2_t*)&bres8[7] + 1);                    \
        *(long2_t*)&areg = g3;                                                  \
        acc1 = __builtin_amdgcn_mfma_scale_f32_32x32x64_f8f6f4(                 \
            areg, btmp, acc1, 4, 4, 3, sa_[3], 3, sw_[3]);                      \
        if ((JT) != diag_jt) {                                                  \
            _Pragma("unroll")                                                   \
            for (int r = 0; r < 16; ++r) {                                      \
                float v = acc0[r] + acc1[r];                                    \
                INS5(b0, b1, b2, b3, b4, v);                                    \
                float e_; EXPRAW(e_, v);                                        \
                if (r & 1) s1r += e_; else s0r += e_;                           \
            }                                                                   \
        } else {                                                                \
            const int dd2 = i_lane - (j0c + (JT) * 32) - 4 * h;                 \
            _Pragma("unroll")                                                   \
            for (int r = 0; r < 16; ++r) {                                      \
                const int jm = (r & 3) + 8 * (r >> 2);                          \
                float v = acc0[r] + acc1[r];                                    \
                if (dd2 == jm) v = NEG_BIG;                                     \
                INS5(b0, b1, b2, b3, b4, v);                                    \
                float e_; EXPRAW(e_, v);                                        \
                if (r & 1) s1r += e_; else s0r += e_;                           \
            }                                                                   \
        }                                                                       \
        __syncthreads();                                                        \
    }

    for (int jt = 0; jt < NTILE; jt += 2) {
        TILE_BODY(jt, 0);
        TILE_BODY(jt + 1, BUFSZ);
    }
#undef TILE_BODY
#undef MFMA_E
#undef MFMA_O
#undef STAGE
#undef GLL

    float s_run = s0r + s1r;
    // merge the two h-halves: lanes l and l^32 hold complementary j-rows
    s_run += __shfl_xor(s_run, 32);
    {
        float o0 = __shfl_xor(b0, 32), o1 = __shfl_xor(b1, 32), o2 = __shfl_xor(b2, 32),
              o3 = __shfl_xor(b3, 32), o4 = __shfl_xor(b4, 32);
        INS5(b0, b1, b2, b3, b4, o0); INS5(b0, b1, b2, b3, b4, o1);
        INS5(b0, b1, b2, b3, b4, o2); INS5(b0, b1, b2, b3, b4, o3);
        INS5(b0, b1, b2, b3, b4, o4);
    }
    if (h == 0) {
        float* p = pstats + ((size_t)ch * N_ROWS + i_lane) * 8;
        p[0] = s_run; p[1] = b0; p[2] = b1; p[3] = b2; p[4] = b3; p[5] = b4;
        p[6] = 0.f; p[7] = 0.f;
    }
}

// ---------------- K3: per-row merge of 32 chunk partials ----------------
__global__ __launch_bounds__(128) void reduce1(const float* __restrict__ pstats,
                                               float* __restrict__ partial) {
    int row = blockIdx.x * 128 + threadIdx.x;
    float S = 0.f;
    float b0 = NEG_BIG, b1 = NEG_BIG, b2 = NEG_BIG, b3 = NEG_BIG, b4 = NEG_BIG;
#pragma unroll
    for (int c = 0; c < NCHUNK; ++c) {
        const float* p = pstats + ((size_t)c * N_ROWS + row) * 8;
        S += p[0];
        float v0 = p[1], v1 = p[2], v2 = p[3], v3 = p[4], v4 = p[5];
        INS5(b0, b1, b2, b3, b4, v0); INS5(b0, b1, b2, b3, b4, v1);
        INS5(b0, b1, b2, b3, b4, v2); INS5(b0, b1, b2, b3, b4, v3);
        INS5(b0, b1, b2, b3, b4, v4);
    }
    float e0, e1, e2, e3, e4;
    EXPRAW(e0, b0); EXPRAW(e1, b1); EXPRAW(e2, b2); EXPRAW(e3, b3); EXPRAW(e4, b4);
    float S5 = e0 + e1 + e2 + e3 + e4;
    float loss = __logf(S) - __logf(S5);
#pragma unroll
    for (int m = 1; m < 64; m <<= 1) loss += __shfl_xor(loss, m);
    __shared__ float rr[2];
    if ((threadIdx.x & 63) == 0) rr[threadIdx.x >> 6] = loss;
    __syncthreads();
    if (threadIdx.x == 0) partial[blockIdx.x] = rr[0] + rr[1];
}

// ---------------- K4: final mean ----------------
__global__ void reduce2(const float* __restrict__ partial, float* __restrict__ out) {
    float v = partial[threadIdx.x];   // 64 partials
#pragma unroll
    for (int m = 1; m < 64; m <<= 1) v += __shfl_xor(v, m);
    if (threadIdx.x == 0) out[0] = v * (1.0f / N_ROWS);
}

extern "C" void kernel_launch(void* const* d_in, const int* in_sizes, int n_in,
                              void* d_out, int out_size, void* d_ws, size_t ws_size,
                              hipStream_t stream) {
    const float* z = (const float*)d_in[0];
    float* out = (float*)d_out;
    uint8_t* zn4   = (uint8_t*)d_ws;                                     // 4 MB
    uint8_t* sbq   = (uint8_t*)d_ws + (size_t)4 * 1024 * 1024;           // 256 KB
    float* pstats  = (float*)((char*)d_ws + (size_t)4608 * 1024);        // 8 MB
    float* partial = (float*)((char*)d_ws + (size_t)13 * 1024 * 1024);   // 256 B

    norm_kernel<<<N_ROWS / 4, 256, 0, stream>>>(z, zn4, sbq);
    sim_kernel<<<64 * NCHUNK, 256, 0, stream>>>(zn4, sbq, pstats);
    reduce1<<<N_ROWS / 128, 128, 0, stream>>>(pstats, partial);
    reduce2<<<1, 64, 0, stream>>>(partial, out);
}

// Round 18
// 68.778 us; speedup vs baseline: 1.0177x; 1.0177x over previous
//
#include <hip/hip_runtime.h>
#include <stdint.h>

#define N_ROWS 8192
#define D_DIM  1024
#define NEG_BIG -1e30f
#define NCHUNK 16
#define CHUNK_J 512
#define NTILE 16              // 16 j-tiles of 32 cols per chunk

typedef __attribute__((ext_vector_type(16))) float f32x16;
typedef __attribute__((ext_vector_type(8)))  int   i32x8;
typedef __attribute__((ext_vector_type(4)))  int   i32x4;
typedef __attribute__((ext_vector_type(2)))  long  long2_t;

// exp(10v - 10) = exp2(v*C - C), raw v_exp_f32
#define EXPC 14.4269504089f
#define EXPRAW(dst, v) { float _a = fmaf((v), EXPC, -EXPC);                 \
    asm("v_exp_f32 %0, %1" : "=v"(dst) : "v"(_a)); }

// branchless sorted insert of v into descending 5-list, med3 form
#define INS5(b0,b1,b2,b3,b4,v) {                        \
    float _n4 = __builtin_amdgcn_fmed3f(b3, (v), b4);   \
    float _n3 = __builtin_amdgcn_fmed3f(b2, (v), b3);   \
    float _n2 = __builtin_amdgcn_fmed3f(b1, (v), b2);   \
    float _n1 = __builtin_amdgcn_fmed3f(b0, (v), b1);   \
    b0 = fmaxf(b0, (v)); b1 = _n1; b2 = _n2; b3 = _n3; b4 = _n4; }

// e2m1 encode of x (pre-scaled by inv = 2^-s): grid {0,.5,1,1.5,2,3,4,6}
static __device__ inline uint32_t enc4(float x, float inv) {
    float q = fabsf(x) * inv;
    uint32_t n = q < 0.25f ? 0u : (q < 0.75f ? 1u : (q < 1.25f ? 2u : (q < 1.75f ? 3u :
                 (q < 2.5f  ? 4u : (q < 3.5f  ? 5u : (q < 5.0f  ? 6u : 7u))))));
    return n | (x < 0.f ? 8u : 0u);
}

// ---------------- K1: normalize -> MX-fp4 (e2m1 + per-32-block E8M0) --------
__global__ __launch_bounds__(256) void norm_kernel(const float* __restrict__ z,
                                                   uint8_t* __restrict__ zn4,
                                                   uint8_t* __restrict__ sbq) {
    int wave = threadIdx.x >> 6;
    int lane = threadIdx.x & 63;
    int row  = blockIdx.x * 4 + wave;
    const float* zr = z + (size_t)row * D_DIM;
    float4 c[4];
    float ss = 0.f;
#pragma unroll
    for (int i = 0; i < 4; ++i) {
        c[i] = *(const float4*)(zr + i * 256 + lane * 4);
        ss += c[i].x*c[i].x + c[i].y*c[i].y + c[i].z*c[i].z + c[i].w*c[i].w;
    }
#pragma unroll
    for (int m = 1; m < 64; m <<= 1) ss += __shfl_xor(ss, m);
    float scale = 1.0f / fmaxf(sqrtf(ss), 1e-12f);
    const int J = row >> 5, r31 = row & 31;
    uint8_t* db = zn4 + (size_t)J * 16384;
    uint8_t* sb = sbq + (size_t)J * 1024;
#pragma unroll
    for (int i = 0; i < 4; ++i) {
        float x0 = c[i].x*scale, x1 = c[i].y*scale, x2 = c[i].z*scale, x3 = c[i].w*scale;
        float am = fmaxf(fmaxf(fabsf(x0), fabsf(x1)), fmaxf(fabsf(x2), fabsf(x3)));
        am = fmaxf(am, __shfl_xor(am, 1));
        am = fmaxf(am, __shfl_xor(am, 2));
        am = fmaxf(am, __shfl_xor(am, 4));
        uint32_t ub = __float_as_uint(am);
        int sbyte = (int)(ub >> 23) - 2 + (((ub & 0x7fffffu) > 0x400000u) ? 1 : 0);
        float inv = __uint_as_float((uint32_t)(254 - sbyte) << 23);   // 2^-s
        uint32_t pk = enc4(x0, inv) | (enc4(x1, inv) << 4)
                    | (enc4(x2, inv) << 8) | (enc4(x3, inv) << 12);
        uint32_t pko = __shfl_xor(pk, 1);          // partner lane's 16 bits
        int m  = i * 4 + (lane >> 4);
        int l2 = r31 + 32 * ((lane >> 3) & 1);
        if ((lane & 1) == 0)                        // paired 4B store
            *(uint32_t*)(db + m * 1024 + l2 * 16 + 4 * ((lane & 7) >> 1))
                = pk | (pko << 16);
        if ((lane & 7) == 0) {
            int j = lane >> 3;
            sb[(size_t)(r31 + 32 * (j & 1)) * 16 + i * 4 + (j >> 1)] = (uint8_t)sbyte;
        }
    }
}

// ---------------- K2: fused MX-fp4 sim, NO LDS / NO barriers -----------------
// grid: 1024 blocks = 64 i-groups x 16 j-chunks, blockIdx = ib*16 + jg so
// CU-resident blocks (256 apart) share the same jg -> same A-tile stream.
// Each wave: distinct i-tile (Ii = ib*4+w, B resident 64 VGPR); all 4 waves
// sweep the SAME 16 j-tiles in order, A-fragments read DIRECT from L1/L2
// (coalesced 1 KB broadcasts; zn4 = 4 MB, cache-resident) via a depth-6
// rolling register prefetch. Raw s_barrier per tile aligns the 4 waves so
// 3 of 4 A-reads hit L1. No LDS, no __syncthreads, no vmcnt drains.
__global__ __launch_bounds__(256, 2) void sim_kernel(const uint8_t* __restrict__ zn4,
                                                     const uint8_t* __restrict__ sbq,
                                                     float* __restrict__ pstats) {
    const int tid  = threadIdx.x;
    const int w    = tid >> 6;
    const int l    = tid & 63;
    const int r32  = l & 31;
    const int h    = l >> 5;
    const int ib   = blockIdx.x >> 4;
    const int jg   = blockIdx.x & 15;
    const int j0c  = jg * CHUNK_J;
    const int i_lane = ib * 128 + w * 32 + r32;
    const int Ii   = ib * 4 + w;                       // i-tile index 0..255
    const int diag_jt = ((Ii >> 4) == jg) ? (Ii & 15) : -1;

    // resident B-operand, packed pairs (even m lower 4 dwords, odd m upper)
    i32x8 bres8[8];
    {
        const uint8_t* rp = zn4 + (size_t)Ii * 16384 + l * 16;
#pragma unroll
        for (int g = 0; g < 8; ++g) {
            *(long2_t*)&bres8[g]       = *(const long2_t*)(rp + (2 * g) * 1024);
            *((long2_t*)&bres8[g] + 1) = *(const long2_t*)(rp + (2 * g + 1) * 1024);
        }
    }
    uint32_t sw_[4];
    {
        const uint32_t* sp = (const uint32_t*)(sbq + (size_t)Ii * 1024 + l * 16);
        sw_[0] = sp[0]; sw_[1] = sp[1]; sw_[2] = sp[2]; sw_[3] = sp[3];
    }

    // rolling A-prefetch: gbuf[s] low 16 B = fragment for stream slot s
    i32x8 gbuf[6];
    {
        const uint8_t* A0 = zn4 + (size_t)(jg * NTILE) * 16384 + l * 16;
#pragma unroll
        for (int s = 0; s < 6; ++s)
            *(long2_t*)&gbuf[s] = *(const long2_t*)(A0 + s * 1024);
    }
    i32x4 sa_v = *(const i32x4*)(sbq + (size_t)(jg * NTILE) * 1024 + l * 16);

    float s0r = 0.f, s1r = 0.f;
    float b0 = NEG_BIG, b1 = NEG_BIG, b2 = NEG_BIG, b3 = NEG_BIG, b4 = NEG_BIG;
    i32x8 btmp = {0,0,0,0,0,0,0,0};

// MFMA with literal M; consume gbuf[M%6], then refill slot with SRC (next +6)
#define MFMA_E(M, SRC) {                                                        \
        asm volatile("" : "+v"(bres8[(M) >> 1]));                               \
        acc0 = __builtin_amdgcn_mfma_scale_f32_32x32x64_f8f6f4(                 \
            gbuf[(M) % 6], bres8[(M) >> 1], acc0, 4, 4,                         \
            (M) & 3, sa_[(M) >> 2], (M) & 3, sw_[(M) >> 2]);                    \
        *(long2_t*)&gbuf[(M) % 6] = *(const long2_t*)(SRC); }
#define MFMA_O(M, SRC) {                                                        \
        *(long2_t*)&btmp = *((const long2_t*)&bres8[(M) >> 1] + 1);             \
        acc1 = __builtin_amdgcn_mfma_scale_f32_32x32x64_f8f6f4(                 \
            gbuf[(M) % 6], btmp, acc1, 4, 4,                                    \
            (M) & 3, sa_[(M) >> 2], (M) & 3, sw_[(M) >> 2]);                    \
        *(long2_t*)&gbuf[(M) % 6] = *(const long2_t*)(SRC); }

#define TILE_BODY(JT) {                                                         \
        const uint8_t* At  = zn4 + (size_t)(jg * NTILE + (JT)) * 16384 + l * 16;\
        const uint8_t* At1 = zn4 + (size_t)(jg * NTILE + (((JT) + 1) & 15))     \
                             * 16384 + l * 16;                                  \
        uint32_t sa_[4];                                                        \
        sa_[0] = sa_v[0]; sa_[1] = sa_v[1]; sa_[2] = sa_v[2]; sa_[3] = sa_v[3]; \
        sa_v = *(const i32x4*)(sbq + (size_t)(jg * NTILE + (((JT) + 1) & 15))   \
                               * 1024 + l * 16);                                \
        f32x16 acc0, acc1;                                                      \
        _Pragma("unroll")                                                       \
        for (int r = 0; r < 16; ++r) { acc0[r] = 0.f; acc1[r] = 0.f; }          \
        MFMA_E(0,  At + 6 * 1024)   MFMA_O(1,  At + 7 * 1024)                   \
        MFMA_E(2,  At + 8 * 1024)   MFMA_O(3,  At + 9 * 1024)                   \
        MFMA_E(4,  At + 10 * 1024)  MFMA_O(5,  At + 11 * 1024)                  \
        MFMA_E(6,  At + 12 * 1024)  MFMA_O(7,  At + 13 * 1024)                  \
        MFMA_E(8,  At + 14 * 1024)  MFMA_O(9,  At + 15 * 1024)                  \
        MFMA_E(10, At1 + 0 * 1024)  MFMA_O(11, At1 + 1 * 1024)                  \
        MFMA_E(12, At1 + 2 * 1024)  MFMA_O(13, At1 + 3 * 1024)                  \
        MFMA_E(14, At1 + 4 * 1024)  MFMA_O(15, At1 + 5 * 1024)                  \
        if ((JT) != diag_jt) {                                                  \
            _Pragma("unroll")                                                   \
            for (int r = 0; r < 16; ++r) {                                      \
                float v = acc0[r] + acc1[r];                                    \
                INS5(b0, b1, b2, b3, b4, v);                                    \
                float e_; EXPRAW(e_, v);                                        \
                if (r & 1) s1r += e_; else s0r += e_;                           \
            }                                                                   \
        } else {                                                                \
            const int dd2 = i_lane - (j0c + (JT) * 32) - 4 * h;                 \
            _Pragma("unroll")                                                   \
            for (int r = 0; r < 16; ++r) {                                      \
                const int jm = (r & 3) + 8 * (r >> 2);                          \
                float v = acc0[r] + acc1[r];                                    \
                if (dd2 == jm) v = NEG_BIG;                                     \
                INS5(b0, b1, b2, b3, b4, v);                                    \
                float e_; EXPRAW(e_, v);                                        \
                if (r & 1) s1r += e_; else s0r += e_;                           \
            }                                                                   \
        }                                                                       \
        __builtin_amdgcn_s_barrier();   /* align waves for L1 reuse only */     \
    }

    TILE_BODY(0)  TILE_BODY(1)  TILE_BODY(2)  TILE_BODY(3)
    TILE_BODY(4)  TILE_BODY(5)  TILE_BODY(6)  TILE_BODY(7)
    TILE_BODY(8)  TILE_BODY(9)  TILE_BODY(10) TILE_BODY(11)
    TILE_BODY(12) TILE_BODY(13) TILE_BODY(14) TILE_BODY(15)
#undef TILE_BODY
#undef MFMA_E
#undef MFMA_O

    float s_run = s0r + s1r;
    // merge the two h-halves: lanes l and l^32 hold complementary j-rows
    s_run += __shfl_xor(s_run, 32);
    {
        float o0 = __shfl_xor(b0, 32), o1 = __shfl_xor(b1, 32), o2 = __shfl_xor(b2, 32),
              o3 = __shfl_xor(b3, 32), o4 = __shfl_xor(b4, 32);
        INS5(b0, b1, b2, b3, b4, o0); INS5(b0, b1, b2, b3, b4, o1);
        INS5(b0, b1, b2, b3, b4, o2); INS5(b0, b1, b2, b3, b4, o3);
        INS5(b0, b1, b2, b3, b4, o4);
    }
    if (h == 0) {
        float* p = pstats + ((size_t)jg * N_ROWS + i_lane) * 8;
        p[0] = s_run; p[1] = b0; p[2] = b1; p[3] = b2; p[4] = b3; p[5] = b4;
        p[6] = 0.f; p[7] = 0.f;
    }
}

// ---------------- K3: per-row merge of 16 chunk partials ----------------
__global__ __launch_bounds__(128) void reduce1(const float* __restrict__ pstats,
                                               float* __restrict__ partial) {
    int row = blockIdx.x * 128 + threadIdx.x;
    float S = 0.f;
    float b0 = NEG_BIG, b1 = NEG_BIG, b2 = NEG_BIG, b3 = NEG_BIG, b4 = NEG_BIG;
#pragma unroll
    for (int c = 0; c < NCHUNK; ++c) {
        const float* p = pstats + ((size_t)c * N_ROWS + row) * 8;
        S += p[0];
        float v0 = p[1], v1 = p[2], v2 = p[3], v3 = p[4], v4 = p[5];
        INS5(b0, b1, b2, b3, b4, v0); INS5(b0, b1, b2, b3, b4, v1);
        INS5(b0, b1, b2, b3, b4, v2); INS5(b0, b1, b2, b3, b4, v3);
        INS5(b0, b1, b2, b3, b4, v4);
    }
    float e0, e1, e2, e3, e4;
    EXPRAW(e0, b0); EXPRAW(e1, b1); EXPRAW(e2, b2); EXPRAW(e3, b3); EXPRAW(e4, b4);
    float S5 = e0 + e1 + e2 + e3 + e4;
    float loss = __logf(S) - __logf(S5);
#pragma unroll
    for (int m = 1; m < 64; m <<= 1) loss += __shfl_xor(loss, m);
    __shared__ float rr[2];
    if ((threadIdx.x & 63) == 0) rr[threadIdx.x >> 6] = loss;
    __syncthreads();
    if (threadIdx.x == 0) partial[blockIdx.x] = rr[0] + rr[1];
}

// ---------------- K4: final mean ----------------
__global__ void reduce2(const float* __restrict__ partial, float* __restrict__ out) {
    float v = partial[threadIdx.x];   // 64 partials
#pragma unroll
    for (int m = 1; m < 64; m <<= 1) v += __shfl_xor(v, m);
    if (threadIdx.x == 0) out[0] = v * (1.0f / N_ROWS);
}

extern "C" void kernel_launch(void* const* d_in, const int* in_sizes, int n_in,
                              void* d_out, int out_size, void* d_ws, size_t ws_size,
                              hipStream_t stream) {
    const float* z = (const float*)d_in[0];
    float* out = (float*)d_out;
    uint8_t* zn4   = (uint8_t*)d_ws;                                     // 4 MB
    uint8_t* sbq   = (uint8_t*)d_ws + (size_t)4 * 1024 * 1024;           // 256 KB
    float* pstats  = (float*)((char*)d_ws + (size_t)4608 * 1024);        // 4 MB
    float* partial = (float*)((char*)d_ws + (size_t)13 * 1024 * 1024);   // 256 B

    norm_kernel<<<N_ROWS / 4, 256, 0, stream>>>(z, zn4, sbq);
    sim_kernel<<<64 * NCHUNK, 256, 0, stream>>>(zn4, sbq, pstats);
    reduce1<<<N_ROWS / 128, 128, 0, stream>>>(pstats, partial);
    reduce2<<<1, 64, 0, stream>>>(partial, out);
}